// Round 9
// baseline (271.007 us; speedup 1.0000x reference)
//
#include <hip/hip_runtime.h>
#include <hip/hip_bf16.h>

// Problem constants
#define KTOT   268203          // 3*299*299 (odd -> x rows only 4B-aligned)
#define MROWS  256             // B*T = 4*64
#define NCOLS  512             // D1
#define HDIM   28
#define NSTEPS 8382            // ceil(KTOT/32); step 8381 is partial (11 valid k)
#define FSTEP  8381            // number of FULL 32-k steps
#define KREM   11              // KTOT - FSTEP*32
#define BN     128             // N-tile per block (4 blocks cover N=512)

typedef __attribute__((ext_vector_type(4))) float        f32x4;
typedef __attribute__((ext_vector_type(4))) unsigned int u32x4;
typedef __attribute__((ext_vector_type(8))) __bf16       bf16x8;

static __device__ inline bf16x8 pack8(const float* f) {
    union { bf16x8 v; __hip_bfloat16 h[8]; } u;
    #pragma unroll
    for (int j = 0; j < 8; ++j) u.h[j] = __float2bfloat16(f[j]);
    return u.v;
}
static __device__ inline unsigned short bfbits(float v) {
    __hip_bfloat16 h = __float2bfloat16(v);
    union { __hip_bfloat16 h; unsigned short u; } c; c.h = h; return c.u;
}

// -------------------------------------------------------------------------
// Kernel 1: split-K GEMM, 2 blocks/CU (anti-convoy), BM=256 x BN=128.
// 256 threads = 4 waves, each wave owns a 64x128 output tile (acc[4][8]).
// LDS = 80 KB exactly -> two independent blocks per CU, whose pipeline
// stalls overlap (vs one 8-wave barrier convoy in R4..R8).
// A: 32 x 4B global_load_lds per wave (source-swizzled, R4-verified map).
// B: 16 coalesced dword loads/thread -> bf16 -> 2x ds_write_b128 into
//    transposed [col][32] bf16 (k-contiguous b128 frag reads).
// 2-deep pipeline, s_waitcnt vmcnt(48) (one full step always in flight).
// -------------------------------------------------------------------------
__global__ __launch_bounds__(256, 2) void gemm1_kernel(
    const float* __restrict__ x, const float* __restrict__ W1,
    __hip_bfloat16* __restrict__ part, int steps_per, int nks)
{
    __shared__ __align__(16) float          Albuf[2][MROWS * 32];   // 2 x 32 KB
    __shared__ __align__(16) __hip_bfloat16 Blds[2][BN * 32];       // 2 x 8 KB

    const int tid  = threadIdx.x;
    const int lane = tid & 63;
    const int w    = tid >> 6;               // 0..3
    const int wm   = w;                      // wave row (64 rows each)

    // block-id swizzle: the 4 sharers (bx=0..3) of one ks land on one XCD
    int bx, ks;
    {
        const int id = blockIdx.x;
        if ((nks & 7) == 0) {
            const int xcd  = id & 7;
            const int rest = id >> 3;
            bx = rest & 3;
            ks = ((rest >> 2) << 3) | xcd;
        } else {
            bx = id & 3;
            ks = id >> 2;
        }
    }
    const int bcol = bx * BN;

    // ---- A per-lane source offset (R4-verified swizzle: quad g ^ (row&7)) ----
    const int dlt = lane >> 5;               // 0/1
    const int m   = lane & 31;
    const int rw7 = 2 * w + dlt;             // row&7 for every instr i (rows 8i+2w+dlt)
    const int ag  = (m >> 2) ^ rw7;          // logical k-quad this lane fetches
    const size_t a_off = (size_t)rw7 * KTOT + ag * 4 + (m & 3);
    // ---- B per-thread mapping: col = tid&127, k-half = tid>>7 ----
    const int bcl = tid & 127;
    const int bkh = tid >> 7;                // 0/1 : k 0..15 / 16..31

    f32x4 acc[4][8];
    #pragma unroll
    for (int i = 0; i < 4; ++i)
        #pragma unroll
        for (int j = 0; j < 8; ++j)
            acc[i][j] = (f32x4){0.f, 0.f, 0.f, 0.f};

    const int s0 = ks * steps_per;
    int s1 = s0 + steps_per;
    if (s1 > NSTEPS) s1 = NSTEPS;
    int s1f = (s1 < FSTEP) ? s1 : FSTEP;
    int nfull = s1f - s0;
    if (nfull < 0) nfull = 0;

    float bregA[16], bregB[16];

    auto issueA = [&](int s, int buf) {
        const float* ap = x + a_off + (size_t)s * 32;
        #pragma unroll
        for (int i = 0; i < 32; ++i) {       // rows 8i+2w, 8i+2w+1
            const float* gp = ap + (size_t)i * 8 * KTOT;
            char* lp = (char*)&Albuf[buf][0] + (i * 8 + 2 * w) * 128;  // wave-uniform
            __builtin_amdgcn_global_load_lds(
                (const __attribute__((address_space(1))) unsigned int*)(const void*)gp,
                (__attribute__((address_space(3))) unsigned int*)(void*)lp, 4, 0, 0);
        }
    };
    auto loadB = [&](int s, float* breg) {
        const float* bp = W1 + ((size_t)s * 32 + bkh * 16) * NCOLS + bcol + bcl;
        #pragma unroll
        for (int kk = 0; kk < 16; ++kk)
            breg[kk] = bp[(size_t)kk * NCOLS];   // 64 lanes x 4B coalesced
    };
    auto writeB = [&](const float* breg, int buf) {
        unsigned int pk[8];
        #pragma unroll
        for (int q = 0; q < 8; ++q)
            pk[q] = (unsigned int)bfbits(breg[2 * q]) |
                    ((unsigned int)bfbits(breg[2 * q + 1]) << 16);
        __hip_bfloat16* dst = &Blds[buf][bcl * 32 + bkh * 16];
        *(u32x4*)(dst)     = (u32x4){pk[0], pk[1], pk[2], pk[3]};
        *(u32x4*)(dst + 8) = (u32x4){pk[4], pk[5], pk[6], pk[7]};
    };

    auto compute = [&](int buf) {
        const int rc = lane & 15, ko = lane >> 4;
        bf16x8 bq[8];
        #pragma unroll
        for (int ni = 0; ni < 8; ++ni)
            bq[ni] = *(const bf16x8*)&Blds[buf][(ni * 16 + rc) * 32 + ko * 8];
        const int soff = ((2 * ko) ^ (rc & 7)) * 16;
        #pragma unroll
        for (int mi = 0; mi < 4; ++mi) {
            const int ab = (wm * 64 + mi * 16 + rc) * 128;   // row byte base
            float afv[8];
            *(f32x4*)&afv[0] = *(const f32x4*)((const char*)&Albuf[buf][0] + ab + soff);
            *(f32x4*)&afv[4] = *(const f32x4*)((const char*)&Albuf[buf][0] + ab + (soff ^ 16));
            const bf16x8 af = pack8(afv);
            #pragma unroll
            for (int ni = 0; ni < 8; ++ni)
                acc[mi][ni] = __builtin_amdgcn_mfma_f32_16x16x32_bf16(
                    af, bq[ni], acc[mi][ni], 0, 0, 0);
        }
    };

    // ---- main loop over FULL steps (unrolled 2x: static breg/buf) ----
    if (nfull > 0) {
        issueA(s0, 0); loadB(s0, bregA);
        if (nfull > 1) { issueA(s0 + 1, 1); loadB(s0 + 1, bregB); }
        int t = 0;
        for (;;) {
            // ---- even t: buf 0, bregA ----
            if (t + 1 < nfull) { asm volatile("s_waitcnt vmcnt(48)" ::: "memory"); }
            else               { asm volatile("s_waitcnt vmcnt(0)"  ::: "memory"); }
            __builtin_amdgcn_sched_barrier(0);
            writeB(bregA, 0);
            asm volatile("s_waitcnt lgkmcnt(0)" ::: "memory");
            __builtin_amdgcn_sched_barrier(0);
            __builtin_amdgcn_s_barrier();
            __builtin_amdgcn_sched_barrier(0);
            compute(0);
            __builtin_amdgcn_sched_barrier(0);
            __builtin_amdgcn_s_barrier();
            if (t + 2 < nfull) { issueA(s0 + t + 2, 0); loadB(s0 + t + 2, bregA); }
            if (++t >= nfull) break;
            // ---- odd t: buf 1, bregB ----
            if (t + 1 < nfull) { asm volatile("s_waitcnt vmcnt(48)" ::: "memory"); }
            else               { asm volatile("s_waitcnt vmcnt(0)"  ::: "memory"); }
            __builtin_amdgcn_sched_barrier(0);
            writeB(bregB, 1);
            asm volatile("s_waitcnt lgkmcnt(0)" ::: "memory");
            __builtin_amdgcn_sched_barrier(0);
            __builtin_amdgcn_s_barrier();
            __builtin_amdgcn_sched_barrier(0);
            compute(1);
            __builtin_amdgcn_sched_barrier(0);
            __builtin_amdgcn_s_barrier();
            if (t + 2 < nfull) { issueA(s0 + t + 2, 1); loadB(s0 + t + 2, bregB); }
            if (++t >= nfull) break;
        }
    }

    // ---- tail: the single partial step (only its owner runs this) ----
    if (s1 > FSTEP && s0 < s1) {
        const int buf = nfull & 1;
        __syncthreads();
        {   // A: guarded, swizzled scalar writes (row = tid)
            const int row = tid;
            #pragma unroll
            for (int k = 0; k < 32; ++k) {
                const float v = (k < KREM)
                    ? x[(size_t)row * KTOT + (size_t)FSTEP * 32 + k] : 0.f;
                Albuf[buf][row * 32 + ((k >> 2) ^ (row & 7)) * 4 + (k & 3)] = v;
            }
        }
        {   // B: guarded scalar bf16 writes into transposed layout
            #pragma unroll
            for (int i = 0; i < 16; ++i) {
                const int k = bkh * 16 + i;
                const float v = (k < KREM)
                    ? W1[(size_t)(FSTEP * 32 + k) * NCOLS + bcol + bcl] : 0.f;
                Blds[buf][bcl * 32 + k] = __float2bfloat16(v);
            }
        }
        __syncthreads();
        compute(buf);
    }

    // ---- store partials as bf16 (pack column pairs via shfl) ----
    // C/D layout: col = lane&15, row = (lane>>4)*4 + reg
    __hip_bfloat16* outp = part + (size_t)ks * MROWS * NCOLS;
    const int rc = lane & 15, q = lane >> 4;
    #pragma unroll
    for (int mi = 0; mi < 4; ++mi) {
        #pragma unroll
        for (int ni = 0; ni < 8; ++ni) {
            const int col = bcol + ni * 16 + rc;
            #pragma unroll
            for (int j = 0; j < 4; ++j) {
                const int row = wm * 64 + mi * 16 + q * 4 + j;
                const float v  = acc[mi][ni][j];
                const float vh = __shfl_xor(v, 1);
                if (!(rc & 1)) {
                    const unsigned int pk =
                        (unsigned int)bfbits(v) | ((unsigned int)bfbits(vh) << 16);
                    *(unsigned int*)(outp + (size_t)row * NCOLS + col) = pk;
                }
            }
        }
    }
}

// -------------------------------------------------------------------------
// Kernel 2: reduce bf16 split-K partials + b1 + relu -> h1 -> u = h1@Wi
// -------------------------------------------------------------------------
__global__ __launch_bounds__(512) void reduce_u_kernel(
    const __hip_bfloat16* __restrict__ part, const float* __restrict__ b1,
    const float* __restrict__ Wi, float* __restrict__ u, int nks)
{
    __shared__ float h1[NCOLS];
    __shared__ f32x4 red[4][128];
    const int row = blockIdx.x;
    const int tid = threadIdx.x;
    const int c4  = tid & 127;
    const int kk  = tid >> 7;

    const unsigned short* pu = (const unsigned short*)part;
    f32x4 sum = (f32x4){0.f, 0.f, 0.f, 0.f};
    for (int k = kk; k < nks; k += 4) {
        const size_t base = ((size_t)k * MROWS + row) * NCOLS + c4 * 4;
        ushort4 pv = *(const ushort4*)&pu[base];
        union { unsigned int u; float f; } c0, c1, c2, c3;
        c0.u = (unsigned int)pv.x << 16; c1.u = (unsigned int)pv.y << 16;
        c2.u = (unsigned int)pv.z << 16; c3.u = (unsigned int)pv.w << 16;
        sum[0] += c0.f; sum[1] += c1.f; sum[2] += c2.f; sum[3] += c3.f;
    }
    red[kk][c4] = sum;
    __syncthreads();

    if (tid < 128) {
        f32x4 t = red[0][tid] + red[1][tid] + red[2][tid] + red[3][tid];
        const f32x4 bb = *(const f32x4*)&b1[tid * 4];
        t += bb;
        #pragma unroll
        for (int j = 0; j < 4; ++j) h1[tid * 4 + j] = fmaxf(t[j], 0.f);
    }
    __syncthreads();

    const int wv = tid >> 6, lane = tid & 63;
    #pragma unroll
    for (int hh = 0; hh < 4; ++hh) {
        const int h = wv * 4 + hh;
        if (h < HDIM) {
            float p = 0.f;
            #pragma unroll
            for (int dd = 0; dd < 8; ++dd) {
                const int d = lane + dd * 64;
                p += h1[d] * Wi[d * HDIM + h];
            }
            #pragma unroll
            for (int off = 32; off; off >>= 1) p += __shfl_down(p, off);
            if (lane == 0) u[row * HDIM + h] = p;
        }
    }
}

// -------------------------------------------------------------------------
// Kernel 3: LTC recurrence (T=64, fp32, exact reference semantics) + head
// -------------------------------------------------------------------------
__global__ __launch_bounds__(64) void recur_kernel(
    const float* __restrict__ u, const float* __restrict__ Wr,
    const float* __restrict__ br, const float* __restrict__ Av,
    const float* __restrict__ tau, const float* __restrict__ W2,
    const float* __restrict__ b2, float* __restrict__ out)
{
    const int b = blockIdx.x;
    const int j = threadIdx.x;
    const bool act = j < HDIM;
    const int jj = act ? j : 0;

    float wr[HDIM];
    #pragma unroll
    for (int i = 0; i < HDIM; ++i) wr[i] = act ? Wr[i * HDIM + jj] : 0.f;
    const float brj = act ? br[jj] : 0.f;
    const float Aj  = act ? Av[jj] : 0.f;
    const float itj = act ? (1.f / tau[jj]) : 0.f;

    float uv[64];
    #pragma unroll
    for (int t = 0; t < 64; ++t)
        uv[t] = act ? u[(b * 64 + t) * HDIM + jj] : 0.f;

    float h = 0.f;
    #pragma unroll
    for (int t = 0; t < 64; ++t) {
        float a = uv[t] + brj;
        #pragma unroll
        for (int i = 0; i < HDIM; ++i)
            a += __shfl(h, i) * wr[i];
        const float ft = 1.f / (1.f + expf(-a));
        const float hn = (h + ft * Aj) / (1.f + itj + ft);
        h = act ? hn : 0.f;
    }

    const float r  = act ? fmaxf(h, 0.f) : 0.f;
    float p0 = act ? r * W2[jj * 2 + 0] : 0.f;
    float p1 = act ? r * W2[jj * 2 + 1] : 0.f;
    #pragma unroll
    for (int off = 32; off; off >>= 1) {
        p0 += __shfl_down(p0, off);
        p1 += __shfl_down(p1, off);
    }
    if (j == 0) {
        out[b * 2 + 0] = 1.f / (1.f + expf(-(p0 + b2[0])));
        out[b * 2 + 1] = 1.f / (1.f + expf(-(p1 + b2[1])));
    }
}

// -------------------------------------------------------------------------
extern "C" void kernel_launch(void* const* d_in, const int* in_sizes, int n_in,
                              void* d_out, int out_size, void* d_ws, size_t ws_size,
                              hipStream_t stream)
{
    (void)in_sizes; (void)n_in; (void)out_size;
    const float* x   = (const float*)d_in[0];
    const float* W1  = (const float*)d_in[1];
    const float* b1  = (const float*)d_in[2];
    const float* Wi  = (const float*)d_in[3];
    const float* Wr  = (const float*)d_in[4];
    const float* br  = (const float*)d_in[5];
    const float* Av  = (const float*)d_in[6];
    const float* tau = (const float*)d_in[7];
    const float* W2  = (const float*)d_in[8];
    const float* b2  = (const float*)d_in[9];
    float* out = (float*)d_out;

    // nks=128 -> grid 4*128 = 512 blocks = 2 per CU. Partials are bf16.
    const size_t per_split = (size_t)MROWS * NCOLS * sizeof(__hip_bfloat16); // 256 KiB
    int nks = 128;
    while (nks > 8 && (size_t)nks * per_split + (1 << 16) > ws_size) nks >>= 1;
    const int steps_per = (NSTEPS + nks - 1) / nks;

    __hip_bfloat16* part = (__hip_bfloat16*)d_ws;
    float* u = (float*)((char*)d_ws + (size_t)nks * per_split);

    gemm1_kernel<<<dim3(4 * nks), 256, 0, stream>>>(x, W1, part, steps_per, nks);
    reduce_u_kernel<<<dim3(MROWS), 512, 0, stream>>>(part, b1, Wi, u, nks);
    recur_kernel<<<dim3(4), 64, 0, stream>>>(u, Wr, br, Av, tau, W2, b2, out);
}

// Round 10
// 226.517 us; speedup vs baseline: 1.1964x; 1.1964x over previous
//
#include <hip/hip_runtime.h>
#include <hip/hip_bf16.h>

// Problem constants
#define KTOT   268203          // 3*299*299 (odd -> x rows only 4B-aligned)
#define MROWS  256             // B*T = 4*64
#define NCOLS  512             // D1
#define HDIM   28
#define NSTEPS 8382            // ceil(KTOT/32); step 8381 is partial (11 valid k)
#define FSTEP  8381            // number of FULL 32-k steps
#define KREM   11              // KTOT - FSTEP*32
#define BN     256             // N-tile per block (2 blocks cover N=512)
#define BROWS  40              // B LDS row stride in bf16 (80B -> bank spread)

typedef __attribute__((ext_vector_type(4))) float        f32x4;
typedef __attribute__((ext_vector_type(4))) unsigned int u32x4;
typedef __attribute__((ext_vector_type(8))) __bf16       bf16x8;

static __device__ inline bf16x8 pack8(const float* f) {
    union { bf16x8 v; __hip_bfloat16 h[8]; } u;
    #pragma unroll
    for (int j = 0; j < 8; ++j) u.h[j] = __float2bfloat16(f[j]);
    return u.v;
}
static __device__ inline unsigned short bfbits(float v) {
    __hip_bfloat16 h = __float2bfloat16(v);
    union { __hip_bfloat16 h; unsigned short u; } c; c.h = h; return c.u;
}

// -------------------------------------------------------------------------
// Kernel 1: split-K GEMM, BN=256 (traffic floor: x*2 + W1*1), R5's proven
// single-barrier 3-buffer step structure (the only config measured at the
// 10.4 B/cy/CU ingress roofline).
// 512 thr = 8 waves (4x2 grid of 64x128 tiles), acc[4][8].
// A: 16 x 4B global_load_lds / wave (source-swizzled), fp32 [row][32], 3-buf.
// B: 16 coalesced dword loads / wave -> bf16 pack -> 2x ds_write_b128 into
//    [col][40] bf16 (k-contiguous b128 frag reads), 3-buf.
// Step t: vmcnt(32)[A(t) landed, batch(t+1) in flight] ; barrier ;
//         compute(t) ; vmcnt(16)[B-regs(t+1) landed] ; writeB(t+1) ;
//         batch(t+2) ; lgkmcnt(0).
// -------------------------------------------------------------------------
__global__ __launch_bounds__(512, 2) void gemm1_kernel(
    const float* __restrict__ x, const float* __restrict__ W1,
    __hip_bfloat16* __restrict__ part, int steps_per, int nks)
{
    __shared__ __align__(16) float          Albuf[3][MROWS * 32];   // 96 KB
    __shared__ __align__(16) __hip_bfloat16 Blds[3][BN * BROWS];    // 60 KB

    const int tid  = threadIdx.x;
    const int lane = tid & 63;
    const int w    = tid >> 6;
    const int wm   = w >> 1;                 // 0..3 : wave row (64 rows)
    const int wn   = w & 1;                  // 0..1 : wave col (128 cols)

    // block-id swizzle: the 2 sharers (bx=0/1) of one ks land on one XCD
    int bx, ks;
    {
        const int id = blockIdx.x;
        if ((nks & 7) == 0) {
            const int xcd = id & 7;
            const int m_  = id >> 3;
            bx = m_ & 1;
            ks = ((m_ >> 1) << 3) | xcd;
        } else {
            bx = id & 1;
            ks = id >> 1;
        }
    }
    const int bcol = bx * BN;

    // ---- A per-lane source offset (R4-verified swizzle: quad g ^ (row&7)) ----
    const int dlt = lane >> 5;               // 0/1
    const int m   = lane & 31;
    const int rw7 = (2 * w + dlt) & 7;       // == row&7 for every instr i
    const int ag  = (m >> 2) ^ rw7;
    const size_t a_off = (size_t)(2 * w + dlt) * KTOT + ag * 4 + (m & 3);
    // ---- B per-thread mapping: col = (w&3)*64 + lane, k-half = w>>2 ----
    const int bkh = w >> 2;                  // 0/1 : k 0..15 / 16..31
    const int bcl = (w & 3) * 64 + lane;     // 0..255 column within tile

    f32x4 acc[4][8];
    #pragma unroll
    for (int i = 0; i < 4; ++i)
        #pragma unroll
        for (int j = 0; j < 8; ++j)
            acc[i][j] = (f32x4){0.f, 0.f, 0.f, 0.f};

    const int s0 = ks * steps_per;
    int s1 = s0 + steps_per;
    if (s1 > NSTEPS) s1 = NSTEPS;
    int s1f = (s1 < FSTEP) ? s1 : FSTEP;
    int nfull = s1f - s0;
    if (nfull < 0) nfull = 0;

    float breg[16];

    auto loadB = [&](int s) {                // 16 coalesced dword loads (issued FIRST)
        const float* bp = W1 + ((size_t)s * 32 + bkh * 16) * NCOLS + bcol + bcl;
        #pragma unroll
        for (int kk = 0; kk < 16; ++kk)
            breg[kk] = bp[(size_t)kk * NCOLS];
    };
    auto issueA = [&](int s, int buf) {      // 16 x 4B DMA (issued SECOND)
        const float* ap = x + a_off + (size_t)s * 32;
        float* lbase = &Albuf[buf][0];
        #pragma unroll
        for (int i = 0; i < 16; ++i) {
            const float* gp = ap + (size_t)i * 16 * KTOT;
            char* lp = (char*)lbase + (i * 8 + w) * 256;   // wave-uniform
            __builtin_amdgcn_global_load_lds(
                (const __attribute__((address_space(1))) unsigned int*)(const void*)gp,
                (__attribute__((address_space(3))) unsigned int*)(void*)lp, 4, 0, 0);
        }
    };
    auto writeB = [&](int buf) {             // pack bregs -> bf16, 2x b128
        unsigned int pk[8];
        #pragma unroll
        for (int q = 0; q < 8; ++q)
            pk[q] = (unsigned int)bfbits(breg[2 * q]) |
                    ((unsigned int)bfbits(breg[2 * q + 1]) << 16);
        __hip_bfloat16* dst = &Blds[buf][bcl * BROWS + bkh * 16];
        *(u32x4*)(dst)     = (u32x4){pk[0], pk[1], pk[2], pk[3]};
        *(u32x4*)(dst + 8) = (u32x4){pk[4], pk[5], pk[6], pk[7]};
    };

    auto compute = [&](int buf) {
        const int rc = lane & 15, ko = lane >> 4;
        bf16x8 bq[8];
        #pragma unroll
        for (int ni = 0; ni < 8; ++ni)
            bq[ni] = *(const bf16x8*)&Blds[buf][(wn * 128 + ni * 16 + rc) * BROWS + ko * 8];
        const int soff = ((2 * ko) ^ (rc & 7)) * 16;
        const char* abase = (const char*)&Albuf[buf][0];
        #pragma unroll
        for (int mi = 0; mi < 4; ++mi) {
            const int ab = (wm * 64 + mi * 16 + rc) * 128;   // row byte base
            float afv[8];
            *(f32x4*)&afv[0] = *(const f32x4*)(abase + ab + soff);
            *(f32x4*)&afv[4] = *(const f32x4*)(abase + ab + (soff ^ 16));
            const bf16x8 af = pack8(afv);
            #pragma unroll
            for (int ni = 0; ni < 8; ++ni)
                acc[mi][ni] = __builtin_amdgcn_mfma_f32_16x16x32_bf16(
                    af, bq[ni], acc[mi][ni], 0, 0, 0);
        }
    };

    // ---- main loop over FULL steps: single barrier, 3-buffer, deep DMA ----
    if (nfull > 0) {
        // prologue
        loadB(s0); issueA(s0, 0);
        asm volatile("s_waitcnt vmcnt(16)" ::: "memory");   // B-regs(s0) landed
        __builtin_amdgcn_sched_barrier(0);
        writeB(0);
        if (nfull > 1) { loadB(s0 + 1); issueA(s0 + 1, 1); }
        asm volatile("s_waitcnt lgkmcnt(0)" ::: "memory");
        __builtin_amdgcn_sched_barrier(0);

        int buf = 0;
        for (int t = 0; t < nfull; ++t) {
            if (t + 1 < nfull) { asm volatile("s_waitcnt vmcnt(32)" ::: "memory"); }
            else               { asm volatile("s_waitcnt vmcnt(0)"  ::: "memory"); }
            __builtin_amdgcn_sched_barrier(0);
            __builtin_amdgcn_s_barrier();
            __builtin_amdgcn_sched_barrier(0);
            compute(buf);
            __builtin_amdgcn_sched_barrier(0);
            if (t + 1 < nfull) {
                asm volatile("s_waitcnt vmcnt(16)" ::: "memory");  // B-regs(t+1)
                __builtin_amdgcn_sched_barrier(0);
                const int nb = (buf == 2) ? 0 : buf + 1;
                writeB(nb);
                if (t + 2 < nfull) {
                    const int nnb = (nb == 2) ? 0 : nb + 1;
                    loadB(s0 + t + 2); issueA(s0 + t + 2, nnb);
                }
                asm volatile("s_waitcnt lgkmcnt(0)" ::: "memory");
                __builtin_amdgcn_sched_barrier(0);
                buf = nb;
            }
        }
    }

    // ---- tail: the single partial step (only its owner runs this) ----
    if (s1 > FSTEP && s0 < s1) {
        const int buf = nfull % 3;
        __syncthreads();
        {   // A: guarded, swizzled scalar writes
            const int row = tid >> 1, half = tid & 1;
            #pragma unroll
            for (int i = 0; i < 16; ++i) {
                const int k = half * 16 + i;
                const float v = (k < KREM)
                    ? x[(size_t)row * KTOT + (size_t)FSTEP * 32 + k] : 0.f;
                Albuf[buf][row * 32 + ((k >> 2) ^ (row & 7)) * 4 + (k & 3)] = v;
            }
        }
        {   // B: guarded scalar bf16 writes into [col][40]
            const int c = tid & 255, og = tid >> 8;
            #pragma unroll
            for (int i = 0; i < 16; ++i) {
                const int k = og * 16 + i;
                const float v = (k < KREM)
                    ? W1[(size_t)(FSTEP * 32 + k) * NCOLS + bcol + c] : 0.f;
                Blds[buf][c * BROWS + k] = __float2bfloat16(v);
            }
        }
        __syncthreads();
        compute(buf);
    }

    // ---- store partials as bf16 (pack column pairs via shfl) ----
    // C/D layout: col = lane&15, row = (lane>>4)*4 + reg
    __hip_bfloat16* outp = part + (size_t)ks * MROWS * NCOLS;
    const int rc = lane & 15, q = lane >> 4;
    #pragma unroll
    for (int mi = 0; mi < 4; ++mi) {
        #pragma unroll
        for (int ni = 0; ni < 8; ++ni) {
            const int col = bcol + wn * 128 + ni * 16 + rc;
            #pragma unroll
            for (int j = 0; j < 4; ++j) {
                const int row = wm * 64 + mi * 16 + q * 4 + j;
                const float v  = acc[mi][ni][j];
                const float vh = __shfl_xor(v, 1);
                if (!(rc & 1)) {
                    const unsigned int pk =
                        (unsigned int)bfbits(v) | ((unsigned int)bfbits(vh) << 16);
                    *(unsigned int*)(outp + (size_t)row * NCOLS + col) = pk;
                }
            }
        }
    }
}

// -------------------------------------------------------------------------
// Kernel 2: reduce bf16 split-K partials + b1 + relu -> h1 -> u = h1@Wi
// -------------------------------------------------------------------------
__global__ __launch_bounds__(512) void reduce_u_kernel(
    const __hip_bfloat16* __restrict__ part, const float* __restrict__ b1,
    const float* __restrict__ Wi, float* __restrict__ u, int nks)
{
    __shared__ float h1[NCOLS];
    __shared__ f32x4 red[4][128];
    const int row = blockIdx.x;
    const int tid = threadIdx.x;
    const int c4  = tid & 127;
    const int kk  = tid >> 7;

    const unsigned short* pu = (const unsigned short*)part;
    f32x4 sum = (f32x4){0.f, 0.f, 0.f, 0.f};
    for (int k = kk; k < nks; k += 4) {
        const size_t base = ((size_t)k * MROWS + row) * NCOLS + c4 * 4;
        ushort4 pv = *(const ushort4*)&pu[base];
        union { unsigned int u; float f; } c0, c1, c2, c3;
        c0.u = (unsigned int)pv.x << 16; c1.u = (unsigned int)pv.y << 16;
        c2.u = (unsigned int)pv.z << 16; c3.u = (unsigned int)pv.w << 16;
        sum[0] += c0.f; sum[1] += c1.f; sum[2] += c2.f; sum[3] += c3.f;
    }
    red[kk][c4] = sum;
    __syncthreads();

    if (tid < 128) {
        f32x4 t = red[0][tid] + red[1][tid] + red[2][tid] + red[3][tid];
        const f32x4 bb = *(const f32x4*)&b1[tid * 4];
        t += bb;
        #pragma unroll
        for (int j = 0; j < 4; ++j) h1[tid * 4 + j] = fmaxf(t[j], 0.f);
    }
    __syncthreads();

    const int wv = tid >> 6, lane = tid & 63;
    #pragma unroll
    for (int hh = 0; hh < 4; ++hh) {
        const int h = wv * 4 + hh;
        if (h < HDIM) {
            float p = 0.f;
            #pragma unroll
            for (int dd = 0; dd < 8; ++dd) {
                const int d = lane + dd * 64;
                p += h1[d] * Wi[d * HDIM + h];
            }
            #pragma unroll
            for (int off = 32; off; off >>= 1) p += __shfl_down(p, off);
            if (lane == 0) u[row * HDIM + h] = p;
        }
    }
}

// -------------------------------------------------------------------------
// Kernel 3: LTC recurrence (T=64, fp32, exact reference semantics) + head
// -------------------------------------------------------------------------
__global__ __launch_bounds__(64) void recur_kernel(
    const float* __restrict__ u, const float* __restrict__ Wr,
    const float* __restrict__ br, const float* __restrict__ Av,
    const float* __restrict__ tau, const float* __restrict__ W2,
    const float* __restrict__ b2, float* __restrict__ out)
{
    const int b = blockIdx.x;
    const int j = threadIdx.x;
    const bool act = j < HDIM;
    const int jj = act ? j : 0;

    float wr[HDIM];
    #pragma unroll
    for (int i = 0; i < HDIM; ++i) wr[i] = act ? Wr[i * HDIM + jj] : 0.f;
    const float brj = act ? br[jj] : 0.f;
    const float Aj  = act ? Av[jj] : 0.f;
    const float itj = act ? (1.f / tau[jj]) : 0.f;

    float uv[64];
    #pragma unroll
    for (int t = 0; t < 64; ++t)
        uv[t] = act ? u[(b * 64 + t) * HDIM + jj] : 0.f;

    float h = 0.f;
    #pragma unroll
    for (int t = 0; t < 64; ++t) {
        float a = uv[t] + brj;
        #pragma unroll
        for (int i = 0; i < HDIM; ++i)
            a += __shfl(h, i) * wr[i];
        const float ft = 1.f / (1.f + expf(-a));
        const float hn = (h + ft * Aj) / (1.f + itj + ft);
        h = act ? hn : 0.f;
    }

    const float r  = act ? fmaxf(h, 0.f) : 0.f;
    float p0 = act ? r * W2[jj * 2 + 0] : 0.f;
    float p1 = act ? r * W2[jj * 2 + 1] : 0.f;
    #pragma unroll
    for (int off = 32; off; off >>= 1) {
        p0 += __shfl_down(p0, off);
        p1 += __shfl_down(p1, off);
    }
    if (j == 0) {
        out[b * 2 + 0] = 1.f / (1.f + expf(-(p0 + b2[0])));
        out[b * 2 + 1] = 1.f / (1.f + expf(-(p1 + b2[1])));
    }
}

// -------------------------------------------------------------------------
extern "C" void kernel_launch(void* const* d_in, const int* in_sizes, int n_in,
                              void* d_out, int out_size, void* d_ws, size_t ws_size,
                              hipStream_t stream)
{
    (void)in_sizes; (void)n_in; (void)out_size;
    const float* x   = (const float*)d_in[0];
    const float* W1  = (const float*)d_in[1];
    const float* b1  = (const float*)d_in[2];
    const float* Wi  = (const float*)d_in[3];
    const float* Wr  = (const float*)d_in[4];
    const float* br  = (const float*)d_in[5];
    const float* Av  = (const float*)d_in[6];
    const float* tau = (const float*)d_in[7];
    const float* W2  = (const float*)d_in[8];
    const float* b2  = (const float*)d_in[9];
    float* out = (float*)d_out;

    // nks=128 -> grid 2*128 = 256 blocks = 1/CU. Partials are bf16.
    const size_t per_split = (size_t)MROWS * NCOLS * sizeof(__hip_bfloat16); // 256 KiB
    int nks = 128;
    while (nks > 8 && (size_t)nks * per_split + (1 << 16) > ws_size) nks >>= 1;
    const int steps_per = (NSTEPS + nks - 1) / nks;

    __hip_bfloat16* part = (__hip_bfloat16*)d_ws;
    float* u = (float*)((char*)d_ws + (size_t)nks * per_split);

    gemm1_kernel<<<dim3(2 * nks), 512, 0, stream>>>(x, W1, part, steps_per, nks);
    reduce_u_kernel<<<dim3(MROWS), 512, 0, stream>>>(part, b1, Wi, u, nks);
    recur_kernel<<<dim3(4), 64, 0, stream>>>(u, Wr, br, Av, tau, W2, b2, out);
}